// Round 8
// baseline (81.781 us; speedup 1.0000x reference)
//
#include <hip/hip_runtime.h>
#include <math.h>

#define NJ 7
#define DTF 0.01f
#define GRAVF 9.81f

__device__ __forceinline__ void cross3(const float* a, const float* b, float* o){
    o[0] = a[1]*b[2] - a[2]*b[1];
    o[1] = a[2]*b[0] - a[0]*b[2];
    o[2] = a[0]*b[1] - a[1]*b[0];
}
__device__ __forceinline__ void mv3(const float* E, const float* x, float* y){
    y[0] = E[0]*x[0] + E[1]*x[1] + E[2]*x[2];
    y[1] = E[3]*x[0] + E[4]*x[1] + E[5]*x[2];
    y[2] = E[6]*x[0] + E[7]*x[1] + E[8]*x[2];
}
__device__ __forceinline__ void mtv3(const float* E, const float* x, float* y){
    y[0] = E[0]*x[0] + E[3]*x[1] + E[6]*x[2];
    y[1] = E[1]*x[0] + E[4]*x[1] + E[7]*x[2];
    y[2] = E[2]*x[0] + E[5]*x[1] + E[8]*x[2];
}
// y = S x, S sym6 {00,01,02,11,12,22}
__device__ __forceinline__ void symv(const float* S, const float* x, float* y){
    y[0] = S[0]*x[0] + S[1]*x[1] + S[2]*x[2];
    y[1] = S[1]*x[0] + S[3]*x[1] + S[4]*x[2];
    y[2] = S[2]*x[0] + S[4]*x[1] + S[5]*x[2];
}
__device__ __forceinline__ void mm3(const float* A, const float* B, float* o){
#pragma unroll
    for (int r = 0; r < 3; r++)
#pragma unroll
        for (int c = 0; c < 3; c++)
            o[r*3+c] = A[r*3]*B[c] + A[r*3+1]*B[3+c] + A[r*3+2]*B[6+c];
}
// o = A^T B
__device__ __forceinline__ void mtm3(const float* A, const float* B, float* o){
#pragma unroll
    for (int r = 0; r < 3; r++)
#pragma unroll
        for (int c = 0; c < 3; c++)
            o[r*3+c] = A[r]*B[c] + A[3+r]*B[3+c] + A[6+r]*B[6+c];
}
// o = E^T X E (X full 3x3)
__device__ __forceinline__ void congr(const float* E, const float* X, float* o){
    float t[9];
    mtm3(E, X, t);
    mm3(t, E, o);
}
// O = M * skew(p)
__device__ __forceinline__ void skewR(const float* M, const float* p, float* O){
#pragma unroll
    for (int r = 0; r < 3; r++){
        O[r*3+0] = M[r*3+1]*p[2] - M[r*3+2]*p[1];
        O[r*3+1] = M[r*3+2]*p[0] - M[r*3+0]*p[2];
        O[r*3+2] = M[r*3+0]*p[1] - M[r*3+1]*p[0];
    }
}
// O = skew(p) * M
__device__ __forceinline__ void skewL(const float* p, const float* M, float* O){
#pragma unroll
    for (int c = 0; c < 3; c++){
        O[0*3+c] = p[1]*M[2*3+c] - p[2]*M[1*3+c];
        O[1*3+c] = p[2]*M[0*3+c] - p[0]*M[2*3+c];
        O[2*3+c] = p[0]*M[1*3+c] - p[1]*M[0*3+c];
    }
}
__device__ __forceinline__ void symexp(const float* S, float* F){
    F[0]=S[0]; F[1]=S[1]; F[2]=S[2];
    F[3]=S[1]; F[4]=S[3]; F[5]=S[4];
    F[6]=S[2]; F[7]=S[4]; F[8]=S[5];
}
// E = R(q)^T @ R_tree[i]
__device__ __forceinline__ void makeE(const float* a, const float* __restrict__ Rt,
                                      float s, float c, float* E){
    float omc = 1.0f - c;
    float RT[9];
    RT[0] = c + omc*a[0]*a[0];       RT[1] =  s*a[2] + omc*a[0]*a[1]; RT[2] = -s*a[1] + omc*a[0]*a[2];
    RT[3] = -s*a[2] + omc*a[1]*a[0]; RT[4] = c + omc*a[1]*a[1];       RT[5] =  s*a[0] + omc*a[1]*a[2];
    RT[6] =  s*a[1] + omc*a[2]*a[0]; RT[7] = -s*a[0] + omc*a[2]*a[1]; RT[8] = c + omc*a[2]*a[2];
    float Rl[9];
#pragma unroll
    for (int k = 0; k < 9; k++) Rl[k] = Rt[k];
    mm3(RT, Rl, E);
}
// body spatial inertia: Ibar sym6 (SA), h = m*c (3), mass m
__device__ __forceinline__ void bodyI(const float* __restrict__ g_I, int i,
                                      float* SA, float* h, float& m){
    const float* I6 = g_I + i*36;
    SA[0]=I6[0]; SA[1]=I6[1]; SA[2]=I6[2];
    SA[3]=I6[7]; SA[4]=I6[8]; SA[5]=I6[14];
    h[0]=I6[16]; h[1]=I6[5]; h[2]=I6[9];
    m = I6[21];
}

__constant__ float QL_c[NJ] = {-2.9671f,-1.8326f,-2.9671f,-3.1416f,-2.9671f,-0.0873f,-2.9671f};
__constant__ float QU_c[NJ] = { 2.9671f, 1.8326f, 2.9671f, 0.0f,    2.9671f, 3.8223f, 2.9671f};

// ABA, round 2: ALL per-joint state in REGISTERS (full unroll, static indices,
// ZERO LDS instructions). The grid (65536 elem = 1024 waves) pins occupancy at
// 1 wave/SIMD regardless of resources, so the 512-VGPR budget is free — spend
// it to delete every 120cy LDS round-trip and let full unroll batch the
// wave-uniform s_loads across joints. Single code path ~20KB, I$-resident.
__global__ __launch_bounds__(64, 1)
void panda_step(const float* __restrict__ x, const float* __restrict__ u,
                const float* __restrict__ g_ax, const float* __restrict__ g_Rt,
                const float* __restrict__ g_pt, const float* __restrict__ g_I,
                float* __restrict__ out, int B)
{
    const int lane = threadIdx.x;       // block = 64 = 1 wave, no barriers
    const int e    = blockIdx.x*64 + lane;
    if (e >= B) return;

    // ---------------- phase 0: load, clip, sincos ----------------
    float q[NJ], qd[NJ], sn[NJ], cs[NJ], tau[NJ];
    {
        float xl[14];
        const float2* x2 = (const float2*)(x + e*14);
#pragma unroll
        for (int i = 0; i < 7; i++){ float2 v = x2[i]; xl[2*i] = v.x; xl[2*i+1] = v.y; }
#pragma unroll
        for (int i = 0; i < NJ; i++){
            q[i]  = fminf(fmaxf(xl[i], QL_c[i]), QU_c[i]);
            qd[i] = xl[NJ + i];
            __sincosf(q[i], &sn[i], &cs[i]);
            tau[i] = u[e*NJ + i];
        }
    }

    // per-joint state (registers; all indices static via full unroll)
    float vW[NJ][3], vL[NJ][3];          // pass1: spatial velocity [w; v]
    float UtA[NJ][3], UbA[NJ][3];        // pass2: U = IA S
    float ccT[NJ][3], ccB[NJ][3];        // pass2: bias accel c_i
    float di[NJ], uuA[NJ];               // pass2: 1/d, u
    float qdd[NJ];                       // pass3

    // ---------------- pass 1: forward velocities ----------------
    {
        float w[3] = {0.f,0.f,0.f}, vl[3] = {0.f,0.f,0.f};
#pragma unroll
        for (int i = 0; i < NJ; ++i){
            float a[3] = { g_ax[3*i], g_ax[3*i+1], g_ax[3*i+2] };
            float p[3] = { g_pt[3*i], g_pt[3*i+1], g_pt[3*i+2] };
            float E[9]; makeE(a, g_Rt + 9*i, sn[i], cs[i], E);
            float cwp[3]; cross3(w, p, cwp);                 // w x p
            float t[3] = { vl[0]+cwp[0], vl[1]+cwp[1], vl[2]+cwp[2] };
            float nw[3], nl[3];
            mv3(E, w, nw); mv3(E, t, nl);
            nw[0] += a[0]*qd[i]; nw[1] += a[1]*qd[i]; nw[2] += a[2]*qd[i];
#pragma unroll
            for (int k = 0; k < 3; k++){
                vW[i][k] = nw[k]; vL[i][k] = nl[k];
                w[k] = nw[k]; vl[k] = nl[k];
            }
        }
    }

    // ---------------- pass 2: backward articulated inertia ----------------
    {
        float A[6], Bm[9], C[6];             // IA blocks [[A,B],[B^T,C]]
        float px[6] = {0.f,0.f,0.f,0.f,0.f,0.f};
        {
            float SA[6], h[3], m; bodyI(g_I, NJ-1, SA, h, m);
#pragma unroll
            for (int k = 0; k < 6; k++) A[k] = SA[k];
            Bm[0]=0.f;    Bm[1]=-h[2]; Bm[2]= h[1];
            Bm[3]= h[2];  Bm[4]=0.f;   Bm[5]=-h[0];
            Bm[6]=-h[1];  Bm[7]= h[0]; Bm[8]=0.f;
            C[0]=m; C[1]=0.f; C[2]=0.f; C[3]=m; C[4]=0.f; C[5]=m;
        }
#pragma unroll
        for (int i = NJ-1; i >= 0; --i){
            float a[3] = { g_ax[3*i], g_ax[3*i+1], g_ax[3*i+2] };
            float w[3]  = { vW[i][0], vW[i][1], vW[i][2] };
            float vl[3] = { vL[i][0], vL[i][1], vL[i][2] };
            // pA = crf(v) (I_body v) + px
            float SAi[6], hi[3], mi; bodyI(g_I, i, SAi, hi, mi);
            float Ivt[3], hxl[3]; symv(SAi, w, Ivt); cross3(hi, vl, hxl);
#pragma unroll
            for (int k = 0; k < 3; k++) Ivt[k] += hxl[k];
            float hxw[3]; cross3(hi, w, hxw);
            float Ivb[3] = { mi*vl[0]-hxw[0], mi*vl[1]-hxw[1], mi*vl[2]-hxw[2] };
            float c1[3], c2[3], c3[3];
            cross3(w, Ivt, c1); cross3(vl, Ivb, c2); cross3(w, Ivb, c3);
            float pAt[3] = { c1[0]+c2[0]+px[0], c1[1]+c2[1]+px[1], c1[2]+c2[2]+px[2] };
            float pAb[3] = { c3[0]+px[3], c3[1]+px[4], c3[2]+px[5] };
            // U = IA S, d, u
            float Ut[3], Ub[3];
            symv(A, a, Ut); mtv3(Bm, a, Ub);
            float d = a[0]*Ut[0] + a[1]*Ut[1] + a[2]*Ut[2];
            float dinv = __builtin_amdgcn_rcpf(d);
            float uu = tau[i] - (a[0]*pAt[0] + a[1]*pAt[1] + a[2]*pAt[2]);
#pragma unroll
            for (int k = 0; k < 3; k++){ UtA[i][k] = Ut[k]; UbA[i][k] = Ub[k]; }
            di[i] = dinv;
            uuA[i] = uu;
            // c_i = [qd (w x a); qd (vl x a)]
            float wxa[3], lxa[3]; cross3(w, a, wxa); cross3(vl, a, lxa);
            float ct[3] = { qd[i]*wxa[0], qd[i]*wxa[1], qd[i]*wxa[2] };
            float cb[3] = { qd[i]*lxa[0], qd[i]*lxa[1], qd[i]*lxa[2] };
#pragma unroll
            for (int k = 0; k < 3; k++){ ccT[i][k] = ct[k]; ccB[i][k] = cb[k]; }
            if (i > 0){
                float p[3] = { g_pt[3*i], g_pt[3*i+1], g_pt[3*i+2] };
                float E[9]; makeE(a, g_Rt + 9*i, sn[i], cs[i], E);
                // rank-1 deflation: Ia = IA - dinv U U^T
                float rA[6], rB[9], rC[6];
                rA[0]=A[0]-dinv*Ut[0]*Ut[0]; rA[1]=A[1]-dinv*Ut[0]*Ut[1]; rA[2]=A[2]-dinv*Ut[0]*Ut[2];
                rA[3]=A[3]-dinv*Ut[1]*Ut[1]; rA[4]=A[4]-dinv*Ut[1]*Ut[2]; rA[5]=A[5]-dinv*Ut[2]*Ut[2];
#pragma unroll
                for (int r = 0; r < 3; r++)
#pragma unroll
                    for (int c = 0; c < 3; c++)
                        rB[r*3+c] = Bm[r*3+c] - dinv*Ut[r]*Ub[c];
                rC[0]=C[0]-dinv*Ub[0]*Ub[0]; rC[1]=C[1]-dinv*Ub[0]*Ub[1]; rC[2]=C[2]-dinv*Ub[0]*Ub[2];
                rC[3]=C[3]-dinv*Ub[1]*Ub[1]; rC[4]=C[4]-dinv*Ub[1]*Ub[2]; rC[5]=C[5]-dinv*Ub[2]*Ub[2];
                // pa = pA + Ia c + U dinv u
                float du = dinv*uu;
                float t1[3], t2[3];
                symv(rA, ct, t1); mv3(rB, cb, t2);
                float pat[3] = { pAt[0]+t1[0]+t2[0]+du*Ut[0],
                                 pAt[1]+t1[1]+t2[1]+du*Ut[1],
                                 pAt[2]+t1[2]+t2[2]+du*Ut[2] };
                mtv3(rB, ct, t1); symv(rC, cb, t2);
                float pab[3] = { pAb[0]+t1[0]+t2[0]+du*Ub[0],
                                 pAb[1]+t1[1]+t2[1]+du*Ub[1],
                                 pAb[2]+t1[2]+t2[2]+du*Ub[2] };
                // congruences to parent frame
                float Ff[9], AeF[9], CeF[9], tB[9], Bf[9];
                symexp(rA, Ff); congr(E, Ff, AeF);
                symexp(rC, Ff); congr(E, Ff, CeF);
                mtm3(E, rB, tB); mm3(tB, E, Bf);
                float Bp[9], Qm[9], PQ[9], LC[9];
                skewR(Bf, p, Bp);
                skewR(CeF, p, Qm); skewL(p, Qm, PQ);
                skewL(p, CeF, LC);
                // new IA = body(i-1) + X^T Ia X
                float SAm[6], hm[3], mm_; bodyI(g_I, i-1, SAm, hm, mm_);
                A[0] = SAm[0] + AeF[0] - 2.0f*Bp[0]     - PQ[0];
                A[1] = SAm[1] + AeF[1] - (Bp[1]+Bp[3])  - PQ[1];
                A[2] = SAm[2] + AeF[2] - (Bp[2]+Bp[6])  - PQ[2];
                A[3] = SAm[3] + AeF[4] - 2.0f*Bp[4]     - PQ[4];
                A[4] = SAm[4] + AeF[5] - (Bp[5]+Bp[7])  - PQ[5];
                A[5] = SAm[5] + AeF[8] - 2.0f*Bp[8]     - PQ[8];
                Bm[0] = Bf[0]+LC[0];        Bm[1] = Bf[1]+LC[1]-hm[2]; Bm[2] = Bf[2]+LC[2]+hm[1];
                Bm[3] = Bf[3]+LC[3]+hm[2];  Bm[4] = Bf[4]+LC[4];       Bm[5] = Bf[5]+LC[5]-hm[0];
                Bm[6] = Bf[6]+LC[6]-hm[1];  Bm[7] = Bf[7]+LC[7]+hm[0]; Bm[8] = Bf[8]+LC[8];
                C[0] = mm_ + CeF[0]; C[1] = CeF[1]; C[2] = CeF[2];
                C[3] = mm_ + CeF[4]; C[4] = CeF[5]; C[5] = mm_ + CeF[8];
                // px_parent = X^T pa
                float tm[3], tf[3], cp[3];
                mtv3(E, pat, tm); mtv3(E, pab, tf);
                cross3(p, tf, cp);
                px[0]=tm[0]+cp[0]; px[1]=tm[1]+cp[1]; px[2]=tm[2]+cp[2];
                px[3]=tf[0];       px[4]=tf[1];       px[5]=tf[2];
            }
        }
    }

    // ---------------- pass 3: forward accelerations -> qdd ----------------
    {
        float at[3] = {0.f,0.f,0.f}, ab[3] = {0.f,0.f,GRAVF};
#pragma unroll
        for (int i = 0; i < NJ; ++i){
            float a[3] = { g_ax[3*i], g_ax[3*i+1], g_ax[3*i+2] };
            float p[3] = { g_pt[3*i], g_pt[3*i+1], g_pt[3*i+2] };
            float E[9]; makeE(a, g_Rt + 9*i, sn[i], cs[i], E);
            float axp[3]; cross3(at, p, axp);                 // at x p = -p^ at
            float t[3] = { ab[0]+axp[0], ab[1]+axp[1], ab[2]+axp[2] };
            float apt[3], apb[3];
            mv3(E, at, apt); mv3(E, t, apb);
#pragma unroll
            for (int k = 0; k < 3; k++){
                apt[k] += ccT[i][k];
                apb[k] += ccB[i][k];
            }
            float qddi = di[i]*(uuA[i]
                - (UtA[i][0]*apt[0]+UtA[i][1]*apt[1]+UtA[i][2]*apt[2]
                 + UbA[i][0]*apb[0]+UbA[i][1]*apb[1]+UbA[i][2]*apb[2]));
            qdd[i] = qddi;
            at[0] = apt[0] + a[0]*qddi;
            at[1] = apt[1] + a[1]*qddi;
            at[2] = apt[2] + a[2]*qddi;
            ab[0] = apb[0]; ab[1] = apb[1]; ab[2] = apb[2];
        }
    }

    // ---------------- integrate + store ----------------
    {
        float o14[14];
#pragma unroll
        for (int i = 0; i < NJ; i++){
            float qdn = qd[i] + DTF*qdd[i];
            o14[i]      = q[i] + DTF*qdn;
            o14[NJ + i] = qdn;
        }
        float2* o2 = (float2*)(out + e*14);
#pragma unroll
        for (int i = 0; i < 7; i++){ float2 v; v.x = o14[2*i]; v.y = o14[2*i+1]; o2[i] = v; }
    }
}

extern "C" void kernel_launch(void* const* d_in, const int* in_sizes, int n_in,
                              void* d_out, int out_size, void* d_ws, size_t ws_size,
                              hipStream_t stream) {
    const float* x   = (const float*)d_in[0];
    const float* u   = (const float*)d_in[1];
    const float* ax  = (const float*)d_in[2];
    const float* Rt  = (const float*)d_in[3];
    const float* pt  = (const float*)d_in[4];
    const float* Isp = (const float*)d_in[5];
    float* out = (float*)d_out;
    int B = in_sizes[0] / 14;
    int grid = (B + 63) / 64;
    hipLaunchKernelGGL(panda_step, dim3(grid), dim3(64), 0, stream,
                       x, u, ax, Rt, pt, Isp, out, B);
}

// Round 9
// 76.755 us; speedup vs baseline: 1.0655x; 1.0655x over previous
//
#include <hip/hip_runtime.h>
#include <math.h>

#define NJ 7
#define DTF 0.01f
#define GRAVF 9.81f
#define MIX(i,j) ((i)*((i)+1)/2 + (j))
#define FSTR 43   // per-lane F stride (gcd(43,32)=1)
#define SNC  15   // sn/cs stride per role region (gcd(15,32)=1)
#define MRST 35   // M[0:28) + rhs[28:35), stride 35 (gcd(35,32)=1)
#define QDS  7    // qd stride (gcd(7,32)=1)

__device__ __forceinline__ void cross3(const float* a, const float* b, float* o){
    o[0] = a[1]*b[2] - a[2]*b[1];
    o[1] = a[2]*b[0] - a[0]*b[2];
    o[2] = a[0]*b[1] - a[1]*b[0];
}
__device__ __forceinline__ void mv3(const float* E, const float* x, float* y){
    y[0] = E[0]*x[0] + E[1]*x[1] + E[2]*x[2];
    y[1] = E[3]*x[0] + E[4]*x[1] + E[5]*x[2];
    y[2] = E[6]*x[0] + E[7]*x[1] + E[8]*x[2];
}
__device__ __forceinline__ void mtv3(const float* E, const float* x, float* y){
    y[0] = E[0]*x[0] + E[3]*x[1] + E[6]*x[2];
    y[1] = E[1]*x[0] + E[4]*x[1] + E[7]*x[2];
    y[2] = E[2]*x[0] + E[5]*x[1] + E[8]*x[2];
}
__device__ __forceinline__ void symv(const float* S, const float* x, float* y){
    y[0] = S[0]*x[0] + S[1]*x[1] + S[2]*x[2];
    y[1] = S[1]*x[0] + S[3]*x[1] + S[4]*x[2];
    y[2] = S[2]*x[0] + S[4]*x[1] + S[5]*x[2];
}
__device__ __forceinline__ void mm3(const float* A, const float* B, float* o){
#pragma unroll
    for (int r = 0; r < 3; r++)
#pragma unroll
        for (int c = 0; c < 3; c++)
            o[r*3+c] = A[r*3]*B[c] + A[r*3+1]*B[3+c] + A[r*3+2]*B[6+c];
}
// o = E^T X E
__device__ __forceinline__ void congr(const float* E, const float* X, float* o){
    float t[9];
#pragma unroll
    for (int r = 0; r < 3; r++)
#pragma unroll
        for (int c = 0; c < 3; c++)
            t[r*3+c] = E[r]*X[c] + E[3+r]*X[3+c] + E[6+r]*X[6+c];
    mm3(t, E, o);
}
// E_i = R(q_i)^T @ R_tree[i]
__device__ __forceinline__ void makeE(const float* a, const float* __restrict__ Rt,
                                      float s, float c, float* E){
    float omc = 1.0f - c;
    float RT[9];
    RT[0] = c + omc*a[0]*a[0];       RT[1] =  s*a[2] + omc*a[0]*a[1]; RT[2] = -s*a[1] + omc*a[0]*a[2];
    RT[3] = -s*a[2] + omc*a[1]*a[0]; RT[4] = c + omc*a[1]*a[1];       RT[5] =  s*a[0] + omc*a[1]*a[2];
    RT[6] =  s*a[1] + omc*a[2]*a[0]; RT[7] = -s*a[0] + omc*a[2]*a[1]; RT[8] = c + omc*a[2]*a[2];
    float Rl[9];
#pragma unroll
    for (int k = 0; k < 9; k++) Rl[k] = Rt[k];
    mm3(RT, Rl, E);
}
// body spatial-inertia params (wave-uniform scalar loads)
__device__ __forceinline__ void bodyI(const float* __restrict__ g_I, int i,
                                      float* SA, float* h, float& m){
    const float* I6 = g_I + i*36;
    SA[0]=I6[0]; SA[1]=I6[1]; SA[2]=I6[2];
    SA[3]=I6[7]; SA[4]=I6[8]; SA[5]=I6[14];
    h[0]=I6[16]; h[1]=I6[5]; h[2]=I6[9];
    m = I6[21];
}

__constant__ float QL_c[NJ] = {-2.9671f,-1.8326f,-2.9671f,-3.1416f,-2.9671f,-0.0873f,-2.9671f};
__constant__ float QU_c[NJ] = { 2.9671f, 1.8326f, 2.9671f, 0.0f,    2.9671f, 3.8223f, 2.9671f};

// Session-best structure (measured 77.3 us, R5): 64 elem/block, 2 role waves,
// rolled outer loops, ONE barrier total.
//  (1) NO first barrier: each role loads x and computes its own sincos into a
//      per-role LDS region -> role 1 never waits on role 0's global loads.
//  (2) CRBA: M-dots fused into the (statically unrolled, uniform-predicated)
//      F-transform loop -> no separate M-column LDS pass; reads batch for ILP.
//  (3) RNEA backward: accumulated force carried in registers (static indices).
// LDS 40448 B -> 4 blocks/CU.
__global__ __launch_bounds__(128, 2)
void panda_step(const float* __restrict__ x, const float* __restrict__ u,
                const float* __restrict__ g_ax, const float* __restrict__ g_Rt,
                const float* __restrict__ g_pt, const float* __restrict__ g_I,
                float* __restrict__ out, int B)
{
    __shared__ float s_Mr [64*MRST];    // 8960 B  (M triangle + rhs)
    __shared__ float s_F  [2*64*FSTR];  // 22016 B (per-role F)
    __shared__ float s_snc[2*64*SNC];   // 7680 B  (per-role sn/cs)
    __shared__ float s_qd [64*QDS];     // 1792 B  (role 0 only)
    // total 40448 B -> 4 blocks/CU

    const int role = threadIdx.x >> 6;      // wave-uniform
    const int lane = threadIdx.x & 63;
    const int e    = blockIdx.x*64 + lane;
    const bool act = (e < B);
    const int sncb = (role*64 + lane)*SNC;  // per-role sn/cs base

    // ---- phase 0 (both roles, independent): x -> clip -> sincos ----
    float q[NJ], qd[NJ];
    if (act){
        float xl[14];
        const float2* x2 = (const float2*)(x + e*14);
#pragma unroll
        for (int i = 0; i < 7; i++){ float2 v = x2[i]; xl[2*i] = v.x; xl[2*i+1] = v.y; }
#pragma unroll
        for (int i = 0; i < NJ; i++){
            q[i]  = fminf(fmaxf(xl[i], QL_c[i]), QU_c[i]);
            qd[i] = xl[NJ + i];
            float s, c; __sincosf(q[i], &s, &c);
            s_snc[sncb + i]     = s;
            s_snc[sncb + 7 + i] = c;
        }
        if (role == 0){
#pragma unroll
            for (int i = 0; i < NJ; i++){
                s_qd [lane*QDS + i]       = qd[i];
                s_Mr [lane*MRST + 28 + i] = u[e*NJ + i];
            }
        }
    }
    // NO barrier here: every wave consumes only its own LDS region until s_Mr.

    if (act && role == 1){
        // ========== CRBA (rolled outer, fused M-dots, unrolled transform) ==========
        float* Fb = &s_F[(64 + lane)*FSTR];
        float SA[6], hc[3], mc;
        bodyI(g_I, 6, SA, hc, mc);
#pragma unroll 1
        for (int i = NJ-1; i >= 0; --i){
            float a[3] = { g_ax[3*i], g_ax[3*i+1], g_ax[3*i+2] };
            // F_i = [SA a ; a x hc]  (registers)
            float Ft[3]; symv(SA, a, Ft);
            float Fbt[3];
            Fbt[0] = a[1]*hc[2] - a[2]*hc[1];
            Fbt[1] = a[2]*hc[0] - a[0]*hc[2];
            Fbt[2] = a[0]*hc[1] - a[1]*hc[0];
            // M[i][i] from registers (no LDS re-read)
            s_Mr[lane*MRST + (i*(i+3)>>1)] = a[0]*Ft[0] + a[1]*Ft[1] + a[2]*Ft[2];
            Fb[i*6+0]=Ft[0]; Fb[i*6+1]=Ft[1]; Fb[i*6+2]=Ft[2];
            Fb[i*6+3]=Fbt[0]; Fb[i*6+4]=Fbt[1]; Fb[i*6+5]=Fbt[2];
            if (i > 0){
                float p[3] = { g_pt[3*i], g_pt[3*i+1], g_pt[3*i+2] };
                float snv = s_snc[sncb + i], csv = s_snc[sncb + 7 + i];
                float E[9]; makeE(a, g_Rt + 9*i, snv, csv, E);
                float SAm[6], hm[3], mm_;
                bodyI(g_I, i-1, SAm, hm, mm_);
                float Af[9] = {SA[0],SA[1],SA[2], SA[1],SA[3],SA[4], SA[2],SA[4],SA[5]};
                float Ap[9]; congr(E, Af, Ap);
                float hr[3]; mtv3(E, hc, hr);
                float hpd = hr[0]*p[0]+hr[1]*p[1]+hr[2]*p[2];
                float ppd = p[0]*p[0]+p[1]*p[1]+p[2]*p[2];
                float dga = 2.0f*hpd + mc*ppd;
                SA[0] = Ap[0] - 2.0f*p[0]*hr[0] - mc*p[0]*p[0] + dga + SAm[0];
                SA[1] = Ap[1] - p[0]*hr[1] - hr[0]*p[1] - mc*p[0]*p[1] + SAm[1];
                SA[2] = Ap[2] - p[0]*hr[2] - hr[0]*p[2] - mc*p[0]*p[2] + SAm[2];
                SA[3] = Ap[4] - 2.0f*p[1]*hr[1] - mc*p[1]*p[1] + dga + SAm[3];
                SA[4] = Ap[5] - p[1]*hr[2] - hr[1]*p[2] - mc*p[1]*p[2] + SAm[4];
                SA[5] = Ap[8] - 2.0f*p[2]*hr[2] - mc*p[2]*p[2] + dga + SAm[5];
                hc[0] = hr[0] + mc*p[0] + hm[0];
                hc[1] = hr[1] + mc*p[1] + hm[1];
                hc[2] = hr[2] + mc*p[2] + hm[2];
                mc += mm_;
                // next joint's axis for the fused M-dot
                float an[3] = { g_ax[3*(i-1)], g_ax[3*(i-1)+1], g_ax[3*(i-1)+2] };
                // transform active F_k into frame i-1; fused M[k][i-1] dot.
                // k statically unrolled; guard is wave-uniform (i uniform).
#pragma unroll
                for (int k = 0; k < NJ; ++k){
                    if (k >= i){
                        float ft[3]  = {Fb[k*6+0], Fb[k*6+1], Fb[k*6+2]};
                        float fb2[3] = {Fb[k*6+3], Fb[k*6+4], Fb[k*6+5]};
                        float tm[3], tf[3], cp[3];
                        mtv3(E, ft, tm); mtv3(E, fb2, tf);
                        cross3(p, tf, cp);
                        float n0 = tm[0]+cp[0], n1 = tm[1]+cp[1], n2 = tm[2]+cp[2];
                        Fb[k*6+0]=n0; Fb[k*6+1]=n1; Fb[k*6+2]=n2;
                        Fb[k*6+3]=tf[0]; Fb[k*6+4]=tf[1]; Fb[k*6+5]=tf[2];
                        s_Mr[lane*MRST + (k*(k+1)/2) + (i-1)] =
                            an[0]*n0 + an[1]*n1 + an[2]*n2;
                    }
                }
            }
        }
        // ridge + Cholesky factor in registers, store back to s_Mr[0:28)
        float Mx[28];
#pragma unroll
        for (int j = 0; j < 28; j++) Mx[j] = s_Mr[lane*MRST + j];
#pragma unroll
        for (int i = 0; i < NJ; i++) Mx[MIX(i,i)] += 1e-8f;
#pragma unroll
        for (int k = 0; k < NJ; k++){
            float d = Mx[MIX(k,k)];
#pragma unroll
            for (int j = 0; j < NJ; j++) if (j < k) d -= Mx[MIX(k,j)]*Mx[MIX(k,j)];
            float linv = __builtin_amdgcn_rsqf(d);
            Mx[MIX(k,k)] = linv;
#pragma unroll
            for (int i2 = k+1; i2 < NJ; i2++){
                float s2 = Mx[MIX(i2,k)];
#pragma unroll
                for (int j = 0; j < NJ; j++) if (j < k) s2 -= Mx[MIX(i2,j)]*Mx[MIX(k,j)];
                Mx[MIX(i2,k)] = s2 * linv;
            }
        }
#pragma unroll
        for (int j = 0; j < 28; j++) s_Mr[lane*MRST + j] = Mx[j];
    }
    else if (act){
        // =================== RNEA forward (rolled) ===================
        float* Fb = &s_F[lane*FSTR];
        float w[3]  = {0.f,0.f,0.f}, vl[3] = {0.f,0.f,0.f};
        float aw[3] = {0.f,0.f,0.f}, av[3] = {0.f,0.f,GRAVF};
#pragma unroll 1
        for (int i = 0; i < NJ; ++i){
            float a[3] = { g_ax[3*i], g_ax[3*i+1], g_ax[3*i+2] };
            float p[3] = { g_pt[3*i], g_pt[3*i+1], g_pt[3*i+2] };
            float snv = s_snc[sncb + i], csv = s_snc[sncb + 7 + i];
            float qdi = s_qd[lane*QDS + i];
            float E[9]; makeE(a, g_Rt + 9*i, snv, csv, E);
            float tw[3]; mv3(E, w, tw);
            float nw[3] = { tw[0]+a[0]*qdi, tw[1]+a[1]*qdi, tw[2]+a[2]*qdi };
            float cwp[3]; cross3(w, p, cwp);
            float t1[3] = { vl[0]+cwp[0], vl[1]+cwp[1], vl[2]+cwp[2] };
            float nvl[3]; mv3(E, t1, nvl);
            float taw[3]; mv3(E, aw, taw);
            float cna[3]; cross3(nw, a, cna);
            float naw[3] = { taw[0]+qdi*cna[0], taw[1]+qdi*cna[1], taw[2]+qdi*cna[2] };
            float cap[3]; cross3(aw, p, cap);
            float t2[3] = { av[0]+cap[0], av[1]+cap[1], av[2]+cap[2] };
            float tav[3]; mv3(E, t2, tav);
            float cva[3]; cross3(nvl, a, cva);
            float nav[3] = { tav[0]+qdi*cva[0], tav[1]+qdi*cva[1], tav[2]+qdi*cva[2] };
            float SAi[6], hi[3], mi; bodyI(g_I, i, SAi, hi, mi);
            float Ivt[3], Iat[3], hxv[3], hxa[3];
            symv(SAi, nw, Ivt);  cross3(hi, nvl, hxv);
            symv(SAi, naw, Iat); cross3(hi, nav, hxa);
#pragma unroll
            for (int k = 0; k < 3; k++){ Ivt[k] += hxv[k]; Iat[k] += hxa[k]; }
            float hxw[3], hxaw[3];
            cross3(hi, nw, hxw); cross3(hi, naw, hxaw);
            float Ivb[3] = { mi*nvl[0]-hxw[0], mi*nvl[1]-hxw[1], mi*nvl[2]-hxw[2] };
            float Iab[3] = { mi*nav[0]-hxaw[0], mi*nav[1]-hxaw[1], mi*nav[2]-hxaw[2] };
            float c1[3], c2[3], c3[3];
            cross3(nw, Ivt, c1); cross3(nvl, Ivb, c2); cross3(nw, Ivb, c3);
            Fb[i*6+0] = Iat[0]+c1[0]+c2[0];
            Fb[i*6+1] = Iat[1]+c1[1]+c2[1];
            Fb[i*6+2] = Iat[2]+c1[2]+c2[2];
            Fb[i*6+3] = Iab[0]+c3[0];
            Fb[i*6+4] = Iab[1]+c3[1];
            Fb[i*6+5] = Iab[2]+c3[2];
#pragma unroll
            for (int k = 0; k < 3; k++){ w[k]=nw[k]; vl[k]=nvl[k]; aw[k]=naw[k]; av[k]=nav[k]; }
        }
        // ====== RNEA backward: accumulated force in REGISTERS (static idx) ======
        float f[6];
#pragma unroll
        for (int k = 0; k < 6; k++) f[k] = Fb[36 + k];     // F_6
#pragma unroll 1
        for (int i = NJ-1; i >= 1; --i){
            float a[3] = { g_ax[3*i], g_ax[3*i+1], g_ax[3*i+2] };
            s_Mr[lane*MRST + 28 + i] -= a[0]*f[0] + a[1]*f[1] + a[2]*f[2];
            float p[3] = { g_pt[3*i], g_pt[3*i+1], g_pt[3*i+2] };
            float snv = s_snc[sncb + i], csv = s_snc[sncb + 7 + i];
            float E[9]; makeE(a, g_Rt + 9*i, snv, csv, E);
            float ftop[3] = {f[0], f[1], f[2]};
            float fbot[3] = {f[3], f[4], f[5]};
            float tm[3], tf[3], cp[3];
            mtv3(E, ftop, tm); mtv3(E, fbot, tf);
            cross3(p, tf, cp);
            f[0] = Fb[(i-1)*6+0] + tm[0]+cp[0];
            f[1] = Fb[(i-1)*6+1] + tm[1]+cp[1];
            f[2] = Fb[(i-1)*6+2] + tm[2]+cp[2];
            f[3] = Fb[(i-1)*6+3] + tf[0];
            f[4] = Fb[(i-1)*6+4] + tf[1];
            f[5] = Fb[(i-1)*6+5] + tf[2];
        }
        {
            float a0[3] = { g_ax[0], g_ax[1], g_ax[2] };
            s_Mr[lane*MRST + 28] -= a0[0]*f[0] + a0[1]*f[1] + a0[2]*f[2];
        }
    }

    __syncthreads();   // publish Cholesky factor + rhs

    if (act && role == 0){
        // ======== triangular solves + integrate + store ========
        float Mx[28];
#pragma unroll
        for (int j = 0; j < 28; j++) Mx[j] = s_Mr[lane*MRST + j];
        float rhs[NJ];
#pragma unroll
        for (int i = 0; i < NJ; i++) rhs[i] = s_Mr[lane*MRST + 28 + i];
        float y[NJ];
#pragma unroll
        for (int i = 0; i < NJ; i++){
            float s2 = rhs[i];
#pragma unroll
            for (int j = 0; j < NJ; j++) if (j < i) s2 -= Mx[MIX(i,j)]*y[j];
            y[i] = s2 * Mx[MIX(i,i)];
        }
        float z[NJ];
#pragma unroll
        for (int i = NJ-1; i >= 0; i--){
            float s2 = y[i];
#pragma unroll
            for (int j = NJ-1; j >= 0; j--) if (j > i) s2 -= Mx[MIX(j,i)]*z[j];
            z[i] = s2 * Mx[MIX(i,i)];
        }
        float o14[14];
#pragma unroll
        for (int i = 0; i < NJ; i++){
            float qdn = qd[i] + DTF*z[i];
            o14[i]      = q[i] + DTF*qdn;
            o14[NJ + i] = qdn;
        }
        float2* o2 = (float2*)(out + e*14);
#pragma unroll
        for (int i = 0; i < 7; i++){ float2 v; v.x = o14[2*i]; v.y = o14[2*i+1]; o2[i] = v; }
    }
}

extern "C" void kernel_launch(void* const* d_in, const int* in_sizes, int n_in,
                              void* d_out, int out_size, void* d_ws, size_t ws_size,
                              hipStream_t stream) {
    const float* x   = (const float*)d_in[0];
    const float* u   = (const float*)d_in[1];
    const float* ax  = (const float*)d_in[2];
    const float* Rt  = (const float*)d_in[3];
    const float* pt  = (const float*)d_in[4];
    const float* Isp = (const float*)d_in[5];
    float* out = (float*)d_out;
    int B = in_sizes[0] / 14;
    int grid = (B + 63) / 64;
    hipLaunchKernelGGL(panda_step, dim3(grid), dim3(128), 0, stream,
                       x, u, ax, Rt, pt, Isp, out, B);
}